// Round 11
// baseline (172.023 us; speedup 1.0000x reference)
//
#include <hip/hip_runtime.h>

#define BB 8
#define NN 1024
#define DM 256
#define HH 8
#define HD 32
#define TC 768   // 3*DM

typedef __bf16 bf16x8 __attribute__((ext_vector_type(8)));
typedef __bf16 bf16x4 __attribute__((ext_vector_type(4)));
typedef float  f32x4  __attribute__((ext_vector_type(4)));

// ---------------- precast: x -> bf16, W -> W^T bf16 ----------------
__global__ __launch_bounds__(256) void precast(
    const float* __restrict__ x, const float* __restrict__ W,
    __bf16* __restrict__ xb, __bf16* __restrict__ Wt)
{
  const int tid = threadIdx.x;
  const int bid = blockIdx.x;
  if (bid < 48) {
    __shared__ __bf16 T[64][65];
    const int ct = bid % 12, kt = bid / 12;
    const int c0 = ct * 64, k0 = kt * 64;
    #pragma unroll
    for (int i = 0; i < 16; ++i) {         // read coalesced along c
      int e = tid + i * 256, kk = e >> 6, cc = e & 63;
      T[cc][kk] = (__bf16)W[(size_t)(k0 + kk) * TC + c0 + cc];
    }
    __syncthreads();
    #pragma unroll
    for (int i = 0; i < 16; ++i) {         // write coalesced along k
      int e = tid + i * 256, cc = e >> 6, kk = e & 63;
      Wt[(size_t)(c0 + cc) * DM + k0 + kk] = T[cc][kk];
    }
  } else {
    const size_t e = (size_t)(bid - 48) * 256 + tid;   // float4 index
    const float4 v = ((const float4*)x)[e];
    bf16x4 o;
    o[0] = (__bf16)v.x; o[1] = (__bf16)v.y;
    o[2] = (__bf16)v.z; o[3] = (__bf16)v.w;
    ((bf16x4*)xb)[e] = o;
  }
}

// ---------------- QKV projection: bf16 MFMA GEMM + k-prefetch --------------
__global__ __launch_bounds__(256, 4) void qkv_gemm(
    const __bf16* __restrict__ xb, const __bf16* __restrict__ Wt,
    const float* __restrict__ bias, __bf16* __restrict__ Qb,
    __bf16* __restrict__ Kb, __bf16* __restrict__ Vt)
{
  __shared__ __align__(16) char U[18432];          // As+Bs staging, then C tile
  __bf16* As = (__bf16*)U;                         // [128][40]
  __bf16* Bs = (__bf16*)(U + 10240);               // [64][40]

  const int tid  = threadIdx.x;
  const int w    = tid >> 6, lane = tid & 63;
  const int n16  = lane & 15, quad = lane >> 4;
  const int m0   = blockIdx.y * 128, c0 = blockIdx.x * 64;
  const int bb   = m0 >> 10, n0 = m0 & 1023;

  const int arow = tid >> 1, ahalf = tid & 1;
  const int bc   = tid & 63, bkh = tid >> 6;

  f32x4 acc[2][4] = {};

  const __bf16* xa_base = &xb[(size_t)(m0 + arow) * DM + ahalf * 16];
  const __bf16* wb_base = &Wt[(size_t)(c0 + bc) * DM + bkh * 8];
  bf16x8 ra0 = *(const bf16x8*)&xa_base[0];
  bf16x8 ra1 = *(const bf16x8*)&xa_base[8];
  bf16x8 rb  = *(const bf16x8*)&wb_base[0];

  for (int k0 = 0; k0 < DM; k0 += 32) {
    *(bf16x8*)&As[arow*40 + ahalf*16]     = ra0;
    *(bf16x8*)&As[arow*40 + ahalf*16 + 8] = ra1;
    *(bf16x8*)&Bs[bc*40 + bkh*8]          = rb;
    __syncthreads();
    if (k0 + 32 < DM) {        // prefetch next k-tile (in flight over MFMAs)
      ra0 = *(const bf16x8*)&xa_base[k0 + 32];
      ra1 = *(const bf16x8*)&xa_base[k0 + 40];
      rb  = *(const bf16x8*)&wb_base[k0 + 32];
    }
    bf16x8 af0 = *(const bf16x8*)&As[(w*32 + n16)*40 + quad*8];
    bf16x8 af1 = *(const bf16x8*)&As[(w*32 + 16 + n16)*40 + quad*8];
    #pragma unroll
    for (int cb = 0; cb < 4; ++cb) {
      bf16x8 bf = *(const bf16x8*)&Bs[(cb*16 + n16)*40 + quad*8];
      acc[0][cb] = __builtin_amdgcn_mfma_f32_16x16x32_bf16(af0, bf, acc[0][cb], 0, 0, 0);
      acc[1][cb] = __builtin_amdgcn_mfma_f32_16x16x32_bf16(af1, bf, acc[1][cb], 0, 0, 0);
    }
    __syncthreads();
  }

  float bv[4];
  #pragma unroll
  for (int cb = 0; cb < 4; ++cb) bv[cb] = bias[c0 + cb*16 + n16];

  if (c0 < 512) {
    __bf16* Ct = (__bf16*)U;
    #pragma unroll
    for (int cb = 0; cb < 4; ++cb)
      #pragma unroll
      for (int mb = 0; mb < 2; ++mb)
        #pragma unroll
        for (int r = 0; r < 4; ++r)
          Ct[(w*32 + mb*16 + quad*4 + r)*72 + cb*16 + n16] =
              (__bf16)(acc[mb][cb][r] + bv[cb]);
    __syncthreads();
    const int chunk = tid & 3, hh = (tid >> 2) & 1, rbase = tid >> 3;
    const int c_head = c0 + hh*32;
    const int h = (c_head >> 5) & 7;
    __bf16* base = (c_head >> 8) ? Kb : Qb;
    #pragma unroll
    for (int it = 0; it < 4; ++it) {
      int rl = rbase + it*32;
      bf16x8 v = *(const bf16x8*)&Ct[rl*72 + hh*32 + chunk*8];
      *(bf16x8*)&base[((size_t)((bb*HH + h)*NN + n0 + rl))*HD + chunk*8] = v;
    }
  } else {
    __bf16* CtT = (__bf16*)U;
    #pragma unroll
    for (int cb = 0; cb < 4; ++cb)
      #pragma unroll
      for (int mb = 0; mb < 2; ++mb) {
        bf16x4 t;
        #pragma unroll
        for (int r = 0; r < 4; ++r) t[r] = (__bf16)(acc[mb][cb][r] + bv[cb]);
        *(bf16x4*)&CtT[(cb*16 + n16)*136 + w*32 + mb*16 + quad*4] = t;
      }
    __syncthreads();
    const int col = tid >> 2, sg = tid & 3;
    const int c = c0 + col;
    const int h = (c >> 5) & 7, dd = c & 31;
    __bf16* dst = &Vt[((size_t)((bb*HH + h)*HD + dd))*NN + n0 + sg*32];
    const __bf16* srcp = &CtT[col*136 + sg*32];
    #pragma unroll
    for (int q2 = 0; q2 < 4; ++q2)
      *(bf16x8*)&dst[q2*8] = *(const bf16x8*)&srcp[q2*8];
  }
}

// ---------------- fused moire attention (R9 math, split + 8 blocks/CU) -----
// bh-major grid.x (proven L3-friendly), part in grid.y; single-buffered K/V
// (18.9 KB LDS) + __launch_bounds__(256,8) -> 8 blocks/CU capacity.
template <int NJT, bool SPLIT>
__global__ __launch_bounds__(256, 8) void attn_kernel(
    const __bf16* __restrict__ Q, const __bf16* __restrict__ K,
    const __bf16* __restrict__ Vt, const float* __restrict__ adj,
    const int* __restrict__ mask, const float* __restrict__ shifts,
    const float* __restrict__ widths, const float* __restrict__ slw,
    float* __restrict__ out, float* __restrict__ Opart,
    float* __restrict__ lpart)
{
  __shared__ __align__(16) char U[9216];             // Qs (init) then Ps
  __bf16 (*Qs)[40] = (__bf16(*)[40])U;
  __bf16 (*Ps)[72] = (__bf16(*)[72])U;
  __shared__ __align__(16) __bf16 Ks[64][40];        // 5.0 KB single buf
  __shared__ __align__(16) __bf16 Vts[32][72];       // 4.5 KB single buf

  const int tid  = threadIdx.x;
  const int w    = tid >> 6, lane = tid & 63;
  const int n16  = lane & 15, quad = lane >> 4;
  const int bh   = blockIdx.x >> 4, qt = blockIdx.x & 15;
  const int part = blockIdx.y;
  const int b    = bh >> 3, h = bh & 7;
  const int q0   = qt * 64;
  const int jbase = part * NJT * 64;

  const float L2E   = 1.4426950408889634f;
  const float sh    = shifts[h];
  const float ninvw = -L2E / fmaxf(widths[h], 0.5f);
  const float slv   = slw[h] * L2E;
  const float scl   = 0.17677669529663687f * L2E;
  const float MASKV = -28.0f;   // constant: fully-masked rows stay uniform

  const int srow = tid >> 2, sseg = tid & 3;
  const int vd   = tid >> 3, vsg  = tid & 7;

  const __bf16* Kg = K + (size_t)bh*NN*HD;
  const __bf16* Vg = Vt + (size_t)bh*HD*NN;

  {  // stage Q tile + first j-tile (K,V)
    const __bf16* Qg = Q + (size_t)(bh*NN + q0)*HD;
    *(bf16x8*)&Qs[srow][sseg*8] = *(const bf16x8*)&Qg[srow*HD + sseg*8];
    *(bf16x8*)&Ks[srow][sseg*8] =
        *(const bf16x8*)&Kg[(jbase + srow)*HD + sseg*8];
    *(bf16x8*)&Vts[vd][vsg*8] =
        *(const bf16x8*)&Vg[(size_t)vd*NN + jbase + vsg*8];
  }
  int mq[4];
  #pragma unroll
  for (int r = 0; r < 4; ++r) mq[r] = mask[b*NN + q0 + w*16 + quad*4 + r];
  __syncthreads();
  const bf16x8 qf = *(const bf16x8*)&Qs[w*16 + n16][quad*8];
  __syncthreads();   // Qs dead; U becomes Ps

  const f32x4 zero = {0.f, 0.f, 0.f, 0.f};
  float l_r[4] = {0.f, 0.f, 0.f, 0.f};
  f32x4 o0 = zero, o1 = zero;

  const float* adjRow = adj + ((size_t)(b*NN + q0 + w*16 + quad*4))*NN;
  const int*   mrow   = mask + b*NN;

  for (int jtl = 0; jtl < NJT; ++jtl) {
    const int j0 = jbase + jtl * 64;

    bf16x8 kn, vn;
    if (jtl < NJT - 1) {   // prefetch next tile into regs (in flight all iter)
      kn = *(const bf16x8*)&Kg[(j0 + 64 + srow)*HD + sseg*8];
      vn = *(const bf16x8*)&Vg[(size_t)vd*NN + j0 + 64 + vsg*8];
    }

    int mj[4];
    #pragma unroll
    for (int cb = 0; cb < 4; ++cb) mj[cb] = mrow[j0 + cb*16 + n16];
    float av[4][4];
    #pragma unroll
    for (int r = 0; r < 4; ++r)
      #pragma unroll
      for (int cb = 0; cb < 4; ++cb)
        av[r][cb] = adjRow[(size_t)r*NN + j0 + cb*16 + n16];

    f32x4 s[4];
    #pragma unroll
    for (int cb = 0; cb < 4; ++cb) {
      bf16x8 kf = *(const bf16x8*)&Ks[cb*16 + n16][quad*8];
      s[cb] = __builtin_amdgcn_mfma_f32_16x16x32_bf16(qf, kf, zero, 0, 0, 0);
    }

    const bool diagtile = ((part * NJT + jtl) == qt);   // uniform branch
    #pragma unroll
    for (int r = 0; r < 4; ++r) {
      const int rowl = w*16 + quad*4 + r;
      #pragma unroll
      for (int cb = 0; cb < 4; ++cb) {
        float d   = av[r][cb] - sh;
        float mo  = d*d*ninvw;                   // unclamped (R10-validated)
        float val = fmaf(s[cb][r], scl, mo);
        if (diagtile && (cb*16 + n16 == rowl)) val += slv;
        bool ok = (mq[r] != 0) && (mj[cb] != 0);
        val = ok ? val : MASKV;
        float p = __builtin_amdgcn_exp2f(val);
        l_r[r] += p;
        Ps[rowl][cb*16 + n16] = (__bf16)p;
      }
    }

    // PV (Ps rows wave-private; Vts read before the staging barrier)
    bf16x8 a0  = *(const bf16x8*)&Ps[w*16 + n16][quad*8];
    bf16x8 a1  = *(const bf16x8*)&Ps[w*16 + n16][32 + quad*8];
    bf16x8 b00 = *(const bf16x8*)&Vts[n16][quad*8];
    bf16x8 b01 = *(const bf16x8*)&Vts[n16][32 + quad*8];
    bf16x8 b10 = *(const bf16x8*)&Vts[16 + n16][quad*8];
    bf16x8 b11 = *(const bf16x8*)&Vts[16 + n16][32 + quad*8];
    o0 = __builtin_amdgcn_mfma_f32_16x16x32_bf16(a0, b00, o0, 0, 0, 0);
    o0 = __builtin_amdgcn_mfma_f32_16x16x32_bf16(a1, b01, o0, 0, 0, 0);
    o1 = __builtin_amdgcn_mfma_f32_16x16x32_bf16(a0, b10, o1, 0, 0, 0);
    o1 = __builtin_amdgcn_mfma_f32_16x16x32_bf16(a1, b11, o1, 0, 0, 0);

    if (jtl < NJT - 1) {
      __syncthreads();   // everyone done reading Ks/Vts
      *(bf16x8*)&Ks[srow][sseg*8] = kn;
      *(bf16x8*)&Vts[vd][vsg*8]   = vn;
      __syncthreads();   // staged tile visible
    }
  }

  #pragma unroll
  for (int r = 0; r < 4; ++r) {
    float l = l_r[r];
    l += __shfl_xor(l, 1); l += __shfl_xor(l, 2);
    l += __shfl_xor(l, 4); l += __shfl_xor(l, 8);
    const int n = q0 + w*16 + quad*4 + r;
    if (SPLIT) {
      float* og = Opart + ((size_t)(part*BB*HH + bh)*NN + n)*HD;
      og[n16]      = o0[r];
      og[16 + n16] = o1[r];
      if (n16 == 0) lpart[(size_t)(part*BB*HH + bh)*NN + n] = l;
    } else {
      const float invl = 1.0f / l;
      float* og = out + ((size_t)(b*NN + n))*DM + h*HD;
      og[n16]      = o0[r] * invl;
      og[16 + n16] = o1[r] * invl;
    }
  }
}

// combine: out = (O0 + O1) / (l0 + l1)
__global__ __launch_bounds__(256) void combine_kernel(
    const float* __restrict__ Opart, const float* __restrict__ lpart,
    float* __restrict__ out)
{
  const size_t e = (size_t)blockIdx.x * 256 + threadIdx.x;  // float4 index
  const int c = (int)((e << 2) & 255);
  const int n = (int)((e >> 6) & 1023);
  const int b = (int)(e >> 16);
  const int h = c >> 5, d = c & 31;
  const size_t row = (size_t)(b*HH + h)*NN + n;
  const size_t i0  = row*HD + d;
  const size_t ps  = (size_t)BB*HH*NN*HD;
  const float4 a0 = *(const float4*)&Opart[i0];
  const float4 a1 = *(const float4*)&Opart[ps + i0];
  const float  l  = lpart[row] + lpart[(size_t)BB*HH*NN + row];
  const float invl = 1.0f / l;
  float4 o = {(a0.x + a1.x)*invl, (a0.y + a1.y)*invl,
              (a0.z + a1.z)*invl, (a0.w + a1.w)*invl};
  *(float4*)&out[((size_t)(b*NN + n))*DM + c] = o;
}

extern "C" void kernel_launch(void* const* d_in, const int* in_sizes, int n_in,
                              void* d_out, int out_size, void* d_ws, size_t ws_size,
                              hipStream_t stream) {
  const float* x      = (const float*)d_in[0];
  const float* adj    = (const float*)d_in[1];
  const int*   mask   = (const int*)d_in[2];
  const float* W      = (const float*)d_in[3];
  const float* bias   = (const float*)d_in[4];
  const float* shifts = (const float*)d_in[5];
  const float* widths = (const float*)d_in[6];
  const float* slwp   = (const float*)d_in[7];
  float* out = (float*)d_out;

  const size_t BHND = (size_t)BB*HH*NN*HD;          // 2,097,152
  const size_t WTN  = (size_t)TC*DM;                // 196,608
  __bf16* xbuf = (__bf16*)d_ws;                      // [8192,256] bf16
  __bf16* Wt   = xbuf + BHND;                        // [768,256] bf16
  __bf16* Qb   = Wt + WTN;                           // [B,H,N,32]
  __bf16* Kb   = Qb + BHND;
  __bf16* Vt   = Kb + BHND;
  float*  Opart = (float*)(Vt + BHND);
  float*  lpart = Opart + 2*BHND;
  const size_t need = (4*BHND + WTN)*2 + 2*BHND*4 + 2*(size_t)BB*HH*NN*4;

  precast<<<dim3(48 + (int)(BHND/4/256)), 256, 0, stream>>>(x, W, xbuf, Wt);
  qkv_gemm<<<dim3(TC/64, (BB*NN)/128), 256, 0, stream>>>(xbuf, Wt, bias, Qb, Kb, Vt);

  if (ws_size >= need) {
    attn_kernel<8, true><<<dim3(BB*HH*16, 2), 256, 0, stream>>>(
        Qb, Kb, Vt, adj, mask, shifts, widths, slwp, out, Opart, lpart);
    combine_kernel<<<(int)(BHND/4/256), 256, 0, stream>>>(Opart, lpart, out);
  } else {
    attn_kernel<16, false><<<dim3(BB*HH*16, 1), 256, 0, stream>>>(
        Qb, Kb, Vt, adj, mask, shifts, widths, slwp, out, Opart, lpart);
  }
}

// Round 12
// 134.434 us; speedup vs baseline: 1.2796x; 1.2796x over previous
//
#include <hip/hip_runtime.h>

#define BB 8
#define NN 1024
#define DM 256
#define HH 8
#define HD 32
#define TC 768   // 3*DM

typedef __bf16 bf16x8 __attribute__((ext_vector_type(8)));
typedef __bf16 bf16x4 __attribute__((ext_vector_type(4)));
typedef float  f32x4  __attribute__((ext_vector_type(4)));

// ---------------- precast: x -> bf16, W -> W^T bf16 ----------------
__global__ __launch_bounds__(256) void precast(
    const float* __restrict__ x, const float* __restrict__ W,
    __bf16* __restrict__ xb, __bf16* __restrict__ Wt)
{
  const int tid = threadIdx.x;
  const int bid = blockIdx.x;
  if (bid < 48) {
    __shared__ __bf16 T[64][65];
    const int ct = bid % 12, kt = bid / 12;
    const int c0 = ct * 64, k0 = kt * 64;
    #pragma unroll
    for (int i = 0; i < 16; ++i) {         // read coalesced along c
      int e = tid + i * 256, kk = e >> 6, cc = e & 63;
      T[cc][kk] = (__bf16)W[(size_t)(k0 + kk) * TC + c0 + cc];
    }
    __syncthreads();
    #pragma unroll
    for (int i = 0; i < 16; ++i) {         // write coalesced along k
      int e = tid + i * 256, cc = e >> 6, kk = e & 63;
      Wt[(size_t)(c0 + cc) * DM + k0 + kk] = T[cc][kk];
    }
  } else {
    const size_t e = (size_t)(bid - 48) * 256 + tid;   // float4 index
    const float4 v = ((const float4*)x)[e];
    bf16x4 o;
    o[0] = (__bf16)v.x; o[1] = (__bf16)v.y;
    o[2] = (__bf16)v.z; o[3] = (__bf16)v.w;
    ((bf16x4*)xb)[e] = o;
  }
}

// ---------------- QKV projection: bf16 MFMA GEMM + k-prefetch --------------
__global__ __launch_bounds__(256, 4) void qkv_gemm(
    const __bf16* __restrict__ xb, const __bf16* __restrict__ Wt,
    const float* __restrict__ bias, __bf16* __restrict__ Qb,
    __bf16* __restrict__ Kb, __bf16* __restrict__ Vt)
{
  __shared__ __align__(16) char U[18432];          // As+Bs staging, then C tile
  __bf16* As = (__bf16*)U;                         // [128][40]
  __bf16* Bs = (__bf16*)(U + 10240);               // [64][40]

  const int tid  = threadIdx.x;
  const int w    = tid >> 6, lane = tid & 63;
  const int n16  = lane & 15, quad = lane >> 4;
  const int m0   = blockIdx.y * 128, c0 = blockIdx.x * 64;
  const int bb   = m0 >> 10, n0 = m0 & 1023;

  const int arow = tid >> 1, ahalf = tid & 1;
  const int bc   = tid & 63, bkh = tid >> 6;

  f32x4 acc[2][4] = {};

  const __bf16* xa_base = &xb[(size_t)(m0 + arow) * DM + ahalf * 16];
  const __bf16* wb_base = &Wt[(size_t)(c0 + bc) * DM + bkh * 8];
  bf16x8 ra0 = *(const bf16x8*)&xa_base[0];
  bf16x8 ra1 = *(const bf16x8*)&xa_base[8];
  bf16x8 rb  = *(const bf16x8*)&wb_base[0];

  for (int k0 = 0; k0 < DM; k0 += 32) {
    *(bf16x8*)&As[arow*40 + ahalf*16]     = ra0;
    *(bf16x8*)&As[arow*40 + ahalf*16 + 8] = ra1;
    *(bf16x8*)&Bs[bc*40 + bkh*8]          = rb;
    __syncthreads();
    if (k0 + 32 < DM) {        // prefetch next k-tile (in flight over MFMAs)
      ra0 = *(const bf16x8*)&xa_base[k0 + 32];
      ra1 = *(const bf16x8*)&xa_base[k0 + 40];
      rb  = *(const bf16x8*)&wb_base[k0 + 32];
    }
    bf16x8 af0 = *(const bf16x8*)&As[(w*32 + n16)*40 + quad*8];
    bf16x8 af1 = *(const bf16x8*)&As[(w*32 + 16 + n16)*40 + quad*8];
    #pragma unroll
    for (int cb = 0; cb < 4; ++cb) {
      bf16x8 bf = *(const bf16x8*)&Bs[(cb*16 + n16)*40 + quad*8];
      acc[0][cb] = __builtin_amdgcn_mfma_f32_16x16x32_bf16(af0, bf, acc[0][cb], 0, 0, 0);
      acc[1][cb] = __builtin_amdgcn_mfma_f32_16x16x32_bf16(af1, bf, acc[1][cb], 0, 0, 0);
    }
    __syncthreads();
  }

  float bv[4];
  #pragma unroll
  for (int cb = 0; cb < 4; ++cb) bv[cb] = bias[c0 + cb*16 + n16];

  if (c0 < 512) {
    __bf16* Ct = (__bf16*)U;
    #pragma unroll
    for (int cb = 0; cb < 4; ++cb)
      #pragma unroll
      for (int mb = 0; mb < 2; ++mb)
        #pragma unroll
        for (int r = 0; r < 4; ++r)
          Ct[(w*32 + mb*16 + quad*4 + r)*72 + cb*16 + n16] =
              (__bf16)(acc[mb][cb][r] + bv[cb]);
    __syncthreads();
    const int chunk = tid & 3, hh = (tid >> 2) & 1, rbase = tid >> 3;
    const int c_head = c0 + hh*32;
    const int h = (c_head >> 5) & 7;
    __bf16* base = (c_head >> 8) ? Kb : Qb;
    #pragma unroll
    for (int it = 0; it < 4; ++it) {
      int rl = rbase + it*32;
      bf16x8 v = *(const bf16x8*)&Ct[rl*72 + hh*32 + chunk*8];
      *(bf16x8*)&base[((size_t)((bb*HH + h)*NN + n0 + rl))*HD + chunk*8] = v;
    }
  } else {
    __bf16* CtT = (__bf16*)U;
    #pragma unroll
    for (int cb = 0; cb < 4; ++cb)
      #pragma unroll
      for (int mb = 0; mb < 2; ++mb) {
        bf16x4 t;
        #pragma unroll
        for (int r = 0; r < 4; ++r) t[r] = (__bf16)(acc[mb][cb][r] + bv[cb]);
        *(bf16x4*)&CtT[(cb*16 + n16)*136 + w*32 + mb*16 + quad*4] = t;
      }
    __syncthreads();
    const int col = tid >> 2, sg = tid & 3;
    const int c = c0 + col;
    const int h = (c >> 5) & 7, dd = c & 31;
    __bf16* dst = &Vt[((size_t)((bb*HH + h)*HD + dd))*NN + n0 + sg*32];
    const __bf16* srcp = &CtT[col*136 + sg*32];
    #pragma unroll
    for (int q2 = 0; q2 < 4; ++q2)
      *(bf16x8*)&dst[q2*8] = *(const bf16x8*)&srcp[q2*8];
  }
}

// ---------------- fused moire attention (R9 + addr strength-reduction) -----
// block = (b, h, 64-q-row tile); wave w owns q rows [w*16, w*16+16)
__global__ __launch_bounds__(256, 4) void attn_kernel(
    const __bf16* __restrict__ Q, const __bf16* __restrict__ K,
    const __bf16* __restrict__ Vt, const float* __restrict__ adj,
    const int* __restrict__ mask, const float* __restrict__ shifts,
    const float* __restrict__ widths, const float* __restrict__ slw,
    float* __restrict__ out)
{
  __shared__ __align__(16) char U[9216];             // Qs (init) then Ps
  __bf16 (*Qs)[40] = (__bf16(*)[40])U;
  __bf16 (*Ps)[72] = (__bf16(*)[72])U;
  __shared__ __align__(16) __bf16 Ks[2][64][40];     // 10.0 KB double buf
  __shared__ __align__(16) __bf16 Vts[2][32][72];    //  9.0 KB double buf

  const int tid  = threadIdx.x;
  const int w    = tid >> 6, lane = tid & 63;
  const int n16  = lane & 15, quad = lane >> 4;
  const int bh   = blockIdx.x >> 4, qt = blockIdx.x & 15;
  const int b    = bh >> 3, h = bh & 7;
  const int q0   = qt * 64;

  const float L2E   = 1.4426950408889634f;
  const float sh    = shifts[h];
  const float ninvw = -L2E / fmaxf(widths[h], 0.5f);
  const float slv   = slw[h] * L2E;
  const float scl   = 0.17677669529663687f * L2E;
  const float MASKV = -28.0f;   // constant: fully-masked rows stay uniform
  // moire as 2 FMAs: (av-sh)^2*ninvw = fma(av, fma(av,ninvw,c1), c2)
  const float c1 = -2.0f * sh * ninvw;
  const float c2 = sh * sh * ninvw;

  const int srow = tid >> 2, sseg = tid & 3;
  const int vd   = tid >> 3, vsg  = tid & 7;

  {
    const __bf16* Qg = Q + (size_t)(bh*NN + q0)*HD;
    *(bf16x8*)&Qs[srow][sseg*8] = *(const bf16x8*)&Qg[srow*HD + sseg*8];
  }
  const __bf16* Kg = K + (size_t)bh*NN*HD;
  const __bf16* Vg = Vt + (size_t)bh*HD*NN;
  {  // prefetch j-tile 0 into buffer 0
    *(bf16x8*)&Ks[0][srow][sseg*8] = *(const bf16x8*)&Kg[srow*HD + sseg*8];
    *(bf16x8*)&Vts[0][vd][vsg*8]   = *(const bf16x8*)&Vg[(size_t)vd*NN + vsg*8];
  }
  int mq[4];
  #pragma unroll
  for (int r = 0; r < 4; ++r) mq[r] = mask[b*NN + q0 + w*16 + quad*4 + r];
  __syncthreads();
  const bf16x8 qf = *(const bf16x8*)&Qs[w*16 + n16][quad*8];
  __syncthreads();   // Qs dead; U becomes Ps

  const f32x4 zero = {0.f, 0.f, 0.f, 0.f};
  float l_r[4] = {0.f, 0.f, 0.f, 0.f};
  f32x4 o0 = zero, o1 = zero;

  // strength-reduced, lane-resolved row pointers (bumped +64 floats per tile)
  const float* arow0 = adj + ((size_t)(b*NN + q0 + w*16 + quad*4))*NN + n16;
  const float* arow1 = arow0 + NN;
  const float* arow2 = arow0 + 2*NN;
  const float* arow3 = arow0 + 3*NN;
  const int*   mrp   = mask + b*NN + n16;

  #pragma unroll 2
  for (int jtl = 0; jtl < 16; ++jtl) {
    const int cur = jtl & 1;
    const int j0  = jtl * 64;

    bf16x8 kn, vn;
    if (jtl < 15) {   // prefetch next tile into regs
      kn = *(const bf16x8*)&Kg[(j0 + 64 + srow)*HD + sseg*8];
      vn = *(const bf16x8*)&Vg[(size_t)vd*NN + j0 + 64 + vsg*8];
    }

    // adj/mask loads: fixed base + immediate offsets (0/64/128/192 B)
    int mj[4];
    #pragma unroll
    for (int cb = 0; cb < 4; ++cb) mj[cb] = mrp[cb*16];
    float av[4][4];
    #pragma unroll
    for (int cb = 0; cb < 4; ++cb) {
      av[0][cb] = arow0[cb*16];
      av[1][cb] = arow1[cb*16];
      av[2][cb] = arow2[cb*16];
      av[3][cb] = arow3[cb*16];
    }

    f32x4 s[4];
    #pragma unroll
    for (int cb = 0; cb < 4; ++cb) {
      bf16x8 kf = *(const bf16x8*)&Ks[cur][cb*16 + n16][quad*8];
      s[cb] = __builtin_amdgcn_mfma_f32_16x16x32_bf16(qf, kf, zero, 0, 0, 0);
    }

    const bool diagtile = (jtl == qt);   // uniform branch
    #pragma unroll
    for (int r = 0; r < 4; ++r) {
      const int rowl = w*16 + quad*4 + r;
      #pragma unroll
      for (int cb = 0; cb < 4; ++cb) {
        float a   = av[r][cb];
        float mo  = fmaf(a, fmaf(a, ninvw, c1), c2);   // 2-FMA moire
        float val = fmaf(s[cb][r], scl, mo);
        if (diagtile && (cb*16 + n16 == rowl)) val += slv;
        bool ok = (mq[r] != 0) && (mj[cb] != 0);
        val = ok ? val : MASKV;
        float p = __builtin_amdgcn_exp2f(val);
        l_r[r] += p;
        Ps[rowl][cb*16 + n16] = (__bf16)p;
      }
    }

    bf16x8 a0  = *(const bf16x8*)&Ps[w*16 + n16][quad*8];
    bf16x8 a1  = *(const bf16x8*)&Ps[w*16 + n16][32 + quad*8];
    bf16x8 b00 = *(const bf16x8*)&Vts[cur][n16][quad*8];
    bf16x8 b01 = *(const bf16x8*)&Vts[cur][n16][32 + quad*8];
    bf16x8 b10 = *(const bf16x8*)&Vts[cur][16 + n16][quad*8];
    bf16x8 b11 = *(const bf16x8*)&Vts[cur][16 + n16][32 + quad*8];
    o0 = __builtin_amdgcn_mfma_f32_16x16x32_bf16(a0, b00, o0, 0, 0, 0);
    o0 = __builtin_amdgcn_mfma_f32_16x16x32_bf16(a1, b01, o0, 0, 0, 0);
    o1 = __builtin_amdgcn_mfma_f32_16x16x32_bf16(a0, b10, o1, 0, 0, 0);
    o1 = __builtin_amdgcn_mfma_f32_16x16x32_bf16(a1, b11, o1, 0, 0, 0);

    if (jtl < 15) {
      *(bf16x8*)&Ks[1 - cur][srow][sseg*8] = kn;
      *(bf16x8*)&Vts[1 - cur][vd][vsg*8]   = vn;
    }
    arow0 += 64; arow1 += 64; arow2 += 64; arow3 += 64; mrp += 64;
    __syncthreads();   // single barrier per j-tile
  }

  #pragma unroll
  for (int r = 0; r < 4; ++r) {
    float l = l_r[r];
    l += __shfl_xor(l, 1); l += __shfl_xor(l, 2);
    l += __shfl_xor(l, 4); l += __shfl_xor(l, 8);
    const float invl = 1.0f / l;
    const int n = q0 + w*16 + quad*4 + r;
    float* og = out + ((size_t)(b*NN + n))*DM + h*HD;
    og[n16]      = o0[r] * invl;
    og[16 + n16] = o1[r] * invl;
  }
}

extern "C" void kernel_launch(void* const* d_in, const int* in_sizes, int n_in,
                              void* d_out, int out_size, void* d_ws, size_t ws_size,
                              hipStream_t stream) {
  const float* x      = (const float*)d_in[0];
  const float* adj    = (const float*)d_in[1];
  const int*   mask   = (const int*)d_in[2];
  const float* W      = (const float*)d_in[3];
  const float* bias   = (const float*)d_in[4];
  const float* shifts = (const float*)d_in[5];
  const float* widths = (const float*)d_in[6];
  const float* slwp   = (const float*)d_in[7];
  float* out = (float*)d_out;

  const size_t BHND = (size_t)BB*HH*NN*HD;          // 2,097,152
  const size_t WTN  = (size_t)TC*DM;                // 196,608
  __bf16* xbuf = (__bf16*)d_ws;                      // [8192,256] bf16
  __bf16* Wt   = xbuf + BHND;                        // [768,256] bf16
  __bf16* Qb   = Wt + WTN;                           // [B,H,N,32]
  __bf16* Kb   = Qb + BHND;
  __bf16* Vt   = Kb + BHND;

  precast<<<dim3(48 + (int)(BHND/4/256)), 256, 0, stream>>>(x, W, xbuf, Wt);
  qkv_gemm<<<dim3(TC/64, (BB*NN)/128), 256, 0, stream>>>(xbuf, Wt, bias, Qb, Kb, Vt);
  attn_kernel<<<dim3(BB*HH*16), 256, 0, stream>>>(Qb, Kb, Vt, adj, mask,
                                                  shifts, widths, slwp, out);
}